// Round 14
// baseline (310.238 us; speedup 1.0000x reference)
//
#include <hip/hip_runtime.h>

#define B_ 4
#define N_ 384
#define D_ 64
#define H_ 64
#define BN_ (B_ * N_)   // 1536
#define ROW_ (N_ * H_)  // 24576 floats per batch of PA/PC
#define NTP_ 12         // 32-row j-tile-pairs per batch
#define LDW_ 68         // padded LDS row stride in words (64+4: 2-way max)

typedef float f32x4 __attribute__((ext_vector_type(4)));
typedef _Float16 half8 __attribute__((ext_vector_type(8)));
typedef __fp16 fp16x2 __attribute__((ext_vector_type(2)));   // cvt_pkrtz result type

union frag_cast { f32x4 f; half8 h; };

// ---------------------------------------------------------------------------
// Kernel A: projections (blocks 0..BN_-1) + W2 hi/lo fragment prep
// (blocks BN_..BN_+7) + done-counter reset (block BN_, t0, atomicExch so the
// reset is visible to device-scope atomics from all XCDs).
// W2F layout: [br][q=nt*4+kt*2+part][lane=64][e=8] f16.
//   B element for lane l, elem e: h = kt*32 + (l>>4)*8 + e, n = nt*16 + (l&15)
// ---------------------------------------------------------------------------
__global__ __launch_bounds__(256) void proj_kernel(
    const float* __restrict__ X, const float* __restrict__ Y,
    const float* __restrict__ Wxx1, const float* __restrict__ bxx1,
    const float* __restrict__ Wyx1, const float* __restrict__ byx1,
    const float* __restrict__ W2xx, const float* __restrict__ W2yx,
    float* __restrict__ PAxx, float* __restrict__ PCxx,
    float* __restrict__ PAyx, float* __restrict__ PCyx,
    _Float16* __restrict__ W2F, unsigned int* __restrict__ counter)
{
    if (blockIdx.x >= BN_) {
        if (blockIdx.x == BN_ && threadIdx.x == 0)
            atomicExch(counter, 0u);             // launch-scoped reset
        int t = (blockIdx.x - BN_) * 256 + threadIdx.x;
        int br = t >> 10;
        int q  = (t >> 6) & 15;
        int l  = t & 63;
        int nt = q >> 2, kt = (q >> 1) & 1, part = q & 1;
        const float* W2 = br ? W2yx : W2xx;
        int n = nt * 16 + (l & 15);
        int g = l >> 4;
        _Float16* dst = W2F + t * 8;
#pragma unroll
        for (int e = 0; e < 8; ++e) {
            int h = kt * 32 + g * 8 + e;
            float v = W2[h * 64 + n];
            _Float16 hi = (_Float16)v;
            _Float16 lo = (_Float16)(v - (float)hi);
            dst[e] = part ? lo : hi;
        }
        return;
    }

    int blk = blockIdx.x;            // b*N + n
    int t = threadIdx.x;
    int which = t >> 6, h = t & 63;

    __shared__ float xrow[64];
    __shared__ float yrow[64];
    if (t < 64) xrow[t] = X[blk * 64 + t];
    else if (t < 128) yrow[t - 64] = Y[blk * 64 + (t - 64)];
    __syncthreads();

    const float* v = (which == 2) ? yrow : xrow;
    const float* W = (which < 2) ? Wxx1 : Wyx1;
    int rowoff = (which & 1) ? 64 : 0;

    float acc = 0.f;
    if (which == 1) acc = bxx1[h];
    if (which == 3) acc = byx1[h];
#pragma unroll
    for (int d = 0; d < 64; ++d)
        acc = fmaf(v[d], W[(rowoff + d) * 64 + h], acc);

    float* dst = (which == 0) ? PAxx : (which == 1) ? PCxx
               : (which == 2) ? PAyx : PCyx;
    dst[blk * 64 + h] = acc;
}

// ---------------------------------------------------------------------------
// Kernel B (r14): r13 pair structure + head FUSED via last-block pattern.
// 768 blocks x 256 thr; block = (br, group of 4 bi); 32 j-rows per barrier
// phase; 4 waves share staged PA tiles via LDS; split-f16 MFMA (3 products),
// fp32-grade (absmax 0.0 since r4).
// After z-store: release fence -> atomicAdd(counter); the LAST block acquires
// and runs the decoder (volatile z reads bypass non-coherent per-XCD L2).
// ---------------------------------------------------------------------------
__global__ __launch_bounds__(256, 3) void pair_mfma_kernel(
    const float* __restrict__ PAxx, const float* __restrict__ PCxx,
    const float* __restrict__ PAyx, const float* __restrict__ PCyx,
    const f32x4* __restrict__ W2F,
    float* __restrict__ zxx, float* __restrict__ zyx,
    const float* __restrict__ b2xx, const float* __restrict__ b2yx,
    const float* __restrict__ Wd1, const float* __restrict__ bd1,
    const float* __restrict__ Wd2, const float* __restrict__ bd2,
    unsigned int* __restrict__ counter, float* __restrict__ out)
{
    // XCD-chunked swizzle (bijective: 768 = 8 * 96)
    int bid = blockIdx.x;
    int blk = (bid & 7) * 96 + (bid >> 3);
    int br = blk / 384;
    int ig = blk % 384;              // i-group: bi = ig*4 + w (never straddles b)
    int t = threadIdx.x;
    int w = t >> 6, l = t & 63;
    int g = l >> 4, m = l & 15;
    int bi = ig * 4 + w;
    int b  = bi / N_;

    const float* PA = br ? PAyx : PAxx;
    const float* PC = br ? PCyx : PCxx;

    __shared__ float lbuf[2][32 * LDW_];   // 2 x 8.7 KB

    // B fragments (all 64 k): bf[nt][kt][part], 16 x half8 = 64 regs.
    half8 bf[4][2][2];
    const f32x4* Wb = W2F + br * 1024;
#pragma unroll
    for (int q = 0; q < 16; ++q) {
        frag_cast u;
        u.f = Wb[q * 64 + l];
        asm volatile("" : "+v"(u.f));
        bf[q >> 2][(q >> 1) & 1][q & 1] = u.h;
    }

    // pc values this lane needs: h = kt*32 + g*8 + {0..7}
    f32x4 pcq[4];
#pragma unroll
    for (int kt = 0; kt < 2; ++kt) {
        pcq[kt * 2 + 0] = *(const f32x4*)(PC + bi * 64 + kt * 32 + g * 8);
        pcq[kt * 2 + 1] = *(const f32x4*)(PC + bi * 64 + kt * 32 + g * 8 + 4);
    }

    float mm[4] = {-3.0e38f, -3.0e38f, -3.0e38f, -3.0e38f};

    // staging: thread t stages rows srow and srow+16, 4-float group scg
    int srow = t >> 4;               // 0..15
    int scg  = t & 15;               // 0..15
    const float* gsrc = PA + b * ROW_ + srow * 64 + scg * 4;  // + pt*2048
    int soff = srow * LDW_ + scg * 4;

    // prologue: stage tile-pair 0 into buf 0
    *(f32x4*)(&lbuf[0][0] + soff) = *(const f32x4*)(gsrc);
    *(f32x4*)(&lbuf[0][0] + soff + 16 * LDW_) = *(const f32x4*)(gsrc + 1024);
    __syncthreads();

    const f32x4 vzero = {0.f, 0.f, 0.f, 0.f};
    int cur = 0;

#pragma unroll 1
    for (int pt = 0; pt < NTP_; ++pt) {
        // issue next tile-pair's loads early (hide under this phase's compute)
        f32x4 gn0, gn1;
        if (pt + 1 < NTP_) {
            gn0 = *(const f32x4*)(gsrc + (pt + 1) * 2048);
            gn1 = *(const f32x4*)(gsrc + (pt + 1) * 2048 + 1024);
        }

        // two 16-row subtiles, sequential (ah/al registers reused)
#pragma unroll
        for (int st = 0; st < 2; ++st) {
            const float* lrd = &lbuf[0][0] + cur * (32 * LDW_)
                             + (st * 16 + m) * LDW_ + g * 8;
            f32x4 s0 = *(const f32x4*)(lrd);
            f32x4 s1 = *(const f32x4*)(lrd + 4);
            f32x4 s2 = *(const f32x4*)(lrd + 32);
            f32x4 s3 = *(const f32x4*)(lrd + 36);

            // A-prep: x = relu(pa + pc); split x = hi + lo (pkrtz).
            half8 ah[2], al[2];
#pragma unroll
            for (int kt = 0; kt < 2; ++kt) {
                f32x4 xa = (kt ? s2 : s0) + pcq[kt * 2 + 0];
                f32x4 xb = (kt ? s3 : s1) + pcq[kt * 2 + 1];
                xa = __builtin_elementwise_max(xa, vzero);
                xb = __builtin_elementwise_max(xb, vzero);
                fp16x2* ahp = (fp16x2*)&ah[kt];
                fp16x2* alp = (fp16x2*)&al[kt];
#pragma unroll
                for (int p2 = 0; p2 < 2; ++p2) {
                    fp16x2 hpa = __builtin_amdgcn_cvt_pkrtz(xa[p2 * 2], xa[p2 * 2 + 1]);
                    fp16x2 hpb = __builtin_amdgcn_cvt_pkrtz(xb[p2 * 2], xb[p2 * 2 + 1]);
                    ahp[p2]     = hpa;
                    ahp[p2 + 2] = hpb;
                    alp[p2]     = __builtin_amdgcn_cvt_pkrtz(xa[p2 * 2]     - (float)hpa[0],
                                                             xa[p2 * 2 + 1] - (float)hpa[1]);
                    alp[p2 + 2] = __builtin_amdgcn_cvt_pkrtz(xb[p2 * 2]     - (float)hpb[0],
                                                             xb[p2 * 2 + 1] - (float)hpb[1]);
                }
            }

            // 4 independent accumulator chains (one per nt), depth 6
#pragma unroll
            for (int nt = 0; nt < 4; ++nt) {
                f32x4 a = {0.f, 0.f, 0.f, 0.f};
#pragma unroll
                for (int kt = 0; kt < 2; ++kt) {
                    a = __builtin_amdgcn_mfma_f32_16x16x32_f16(ah[kt], bf[nt][kt][0], a, 0, 0, 0);
                    a = __builtin_amdgcn_mfma_f32_16x16x32_f16(ah[kt], bf[nt][kt][1], a, 0, 0, 0);
                    a = __builtin_amdgcn_mfma_f32_16x16x32_f16(al[kt], bf[nt][kt][0], a, 0, 0, 0);
                }
                mm[nt] = fmaxf(mm[nt],
                               fmaxf(fmaxf(a[0], a[1]), fmaxf(a[2], a[3])));
            }
        }

        // write next tile-pair into the other buffer; one barrier per phase
        if (pt + 1 < NTP_) {
            *(f32x4*)(&lbuf[0][0] + (cur ^ 1) * (32 * LDW_) + soff) = gn0;
            *(f32x4*)(&lbuf[0][0] + (cur ^ 1) * (32 * LDW_) + soff + 16 * LDW_) = gn1;
        }
        __syncthreads();
        cur ^= 1;
    }

    // reduce across the 4 row groups; then every lane holds all 4 nt maxima
#pragma unroll
    for (int nt = 0; nt < 4; ++nt) {
        float v = mm[nt];
        v = fmaxf(v, __shfl_xor(v, 16));
        v = fmaxf(v, __shfl_xor(v, 32));
        mm[nt] = v;
    }
    // lane l owns output column k=l: select mm[l>>4]
    float z = (l < 32) ? ((l < 16) ? mm[0] : mm[1])
                       : ((l < 48) ? mm[2] : mm[3]);
    (br ? zyx : zxx)[bi * 64 + l] = z;

    // ---- last-block head (fused decoder) ----
    __shared__ unsigned int lastflag;
    __threadfence();                  // release our z stores (device scope)
    __syncthreads();                  // all 256 threads' stores+fences done
    if (t == 0) {
        unsigned int old = atomicAdd(counter, 1u);
        lastflag = (old == gridDim.x - 1) ? 1u : 0u;
    }
    __syncthreads();
    if (lastflag) {
        __threadfence();              // acquire side
        volatile const float* vzxx = zxx;   // sc0/sc1 bypass: coherent reads
        volatile const float* vzyx = zyx;
        __shared__ float sbuf[4][64];
        __shared__ float zxs[64];
        int ig2 = t >> 6, h = t & 63;
        for (int bb = 0; bb < B_; ++bb) {
            float s = 0.f;
            for (int i = ig2; i < N_; i += 4) {
                int idx = (bb * N_ + i) * 64 + h;
                s += vzxx[idx] - vzyx[idx];
            }
            sbuf[ig2][h] = s;
            __syncthreads();
            if (t < 64)
                zxs[t] = sbuf[0][t] + sbuf[1][t] + sbuf[2][t] + sbuf[3][t]
                       + (float)N_ * (b2xx[t] - b2yx[t]);
            __syncthreads();
            if (t < 64) {
                float acc = bd1[t];
#pragma unroll
                for (int d = 0; d < 64; ++d)
                    acc = fmaf(zxs[d], Wd1[d * 64 + t] + Wd1[(64 + d) * 64 + t], acc);
                float h1 = fmaxf(acc, 0.f);
                float r = h1 * Wd2[t];
#pragma unroll
                for (int off = 32; off; off >>= 1) r += __shfl_down(r, off);
                if (t == 0) out[bb] = r + bd2[0];
            }
            __syncthreads();
        }
    }
}

extern "C" void kernel_launch(void* const* d_in, const int* in_sizes, int n_in,
                              void* d_out, int out_size, void* d_ws, size_t ws_size,
                              hipStream_t stream) {
    const float* X    = (const float*)d_in[0];
    const float* Y    = (const float*)d_in[1];
    const float* Wxx1 = (const float*)d_in[2];
    const float* bxx1 = (const float*)d_in[3];
    const float* W2xx = (const float*)d_in[4];
    const float* b2xx = (const float*)d_in[5];
    // d_in[6..9]  = xy branch (dead code)
    const float* Wyx1 = (const float*)d_in[10];
    const float* byx1 = (const float*)d_in[11];
    const float* W2yx = (const float*)d_in[12];
    const float* b2yx = (const float*)d_in[13];
    // d_in[14..17] = yy branch (dead code)
    const float* Wd1  = (const float*)d_in[18];
    const float* bd1  = (const float*)d_in[19];
    const float* Wd2  = (const float*)d_in[20];
    const float* bd2  = (const float*)d_in[21];

    float* ws   = (float*)d_ws;
    float* PAxx = ws;
    float* PCxx = ws + 1 * (BN_ * H_);
    float* PAyx = ws + 2 * (BN_ * H_);
    float* PCyx = ws + 3 * (BN_ * H_);
    float* zxx  = ws + 4 * (BN_ * H_);
    float* zyx  = ws + 5 * (BN_ * H_);
    _Float16* W2F = (_Float16*)(ws + 6 * (BN_ * H_));          // 32 KiB
    unsigned int* counter = (unsigned int*)(ws + 6 * (BN_ * H_) + 8192);

    proj_kernel<<<BN_ + 8, 256, 0, stream>>>(X, Y, Wxx1, bxx1, Wyx1, byx1,
                                             W2xx, W2yx,
                                             PAxx, PCxx, PAyx, PCyx, W2F,
                                             counter);
    pair_mfma_kernel<<<768, 256, 0, stream>>>(PAxx, PCxx, PAyx, PCyx,
                                              (const f32x4*)W2F, zxx, zyx,
                                              b2xx, b2yx, Wd1, bd1, Wd2, bd2,
                                              counter, (float*)d_out);
}

// Round 15
// 161.530 us; speedup vs baseline: 1.9206x; 1.9206x over previous
//
#include <hip/hip_runtime.h>

#define B_ 4
#define N_ 384
#define D_ 64
#define H_ 64
#define BN_ (B_ * N_)   // 1536
#define ROW_ (N_ * H_)  // 24576 floats per batch of PA/PC
#define NTP_ 12         // 32-row j-tile-pairs per batch
#define LDW_ 68         // padded LDS row stride in words (64+4: 2-way max)

typedef float f32x4 __attribute__((ext_vector_type(4)));
typedef _Float16 half8 __attribute__((ext_vector_type(8)));
typedef __fp16 fp16x2 __attribute__((ext_vector_type(2)));   // cvt_pkrtz result type

union frag_cast { f32x4 f; half8 h; };

// ---------------------------------------------------------------------------
// Kernel A: projections (blocks 0..BN_-1) + W2 hi/lo fragment prep
// (blocks BN_..BN_+7) + done-counter reset (block BN_, t0).
// W2F layout: [br][q=nt*4+kt*2+part][lane=64][e=8] f16.
//   B element for lane l, elem e: h = kt*32 + (l>>4)*8 + e, n = nt*16 + (l&15)
// ---------------------------------------------------------------------------
__global__ __launch_bounds__(256) void proj_kernel(
    const float* __restrict__ X, const float* __restrict__ Y,
    const float* __restrict__ Wxx1, const float* __restrict__ bxx1,
    const float* __restrict__ Wyx1, const float* __restrict__ byx1,
    const float* __restrict__ W2xx, const float* __restrict__ W2yx,
    float* __restrict__ PAxx, float* __restrict__ PCxx,
    float* __restrict__ PAyx, float* __restrict__ PCyx,
    _Float16* __restrict__ W2F, unsigned int* __restrict__ counter)
{
    if (blockIdx.x >= BN_) {
        if (blockIdx.x == BN_ && threadIdx.x == 0)
            atomicExch(counter, 0u);             // launch-scoped reset
        int t = (blockIdx.x - BN_) * 256 + threadIdx.x;
        int br = t >> 10;
        int q  = (t >> 6) & 15;
        int l  = t & 63;
        int nt = q >> 2, kt = (q >> 1) & 1, part = q & 1;
        const float* W2 = br ? W2yx : W2xx;
        int n = nt * 16 + (l & 15);
        int g = l >> 4;
        _Float16* dst = W2F + t * 8;
#pragma unroll
        for (int e = 0; e < 8; ++e) {
            int h = kt * 32 + g * 8 + e;
            float v = W2[h * 64 + n];
            _Float16 hi = (_Float16)v;
            _Float16 lo = (_Float16)(v - (float)hi);
            dst[e] = part ? lo : hi;
        }
        return;
    }

    int blk = blockIdx.x;            // b*N + n
    int t = threadIdx.x;
    int which = t >> 6, h = t & 63;

    __shared__ float xrow[64];
    __shared__ float yrow[64];
    if (t < 64) xrow[t] = X[blk * 64 + t];
    else if (t < 128) yrow[t - 64] = Y[blk * 64 + (t - 64)];
    __syncthreads();

    const float* v = (which == 2) ? yrow : xrow;
    const float* W = (which < 2) ? Wxx1 : Wyx1;
    int rowoff = (which & 1) ? 64 : 0;

    float acc = 0.f;
    if (which == 1) acc = bxx1[h];
    if (which == 3) acc = byx1[h];
#pragma unroll
    for (int d = 0; d < 64; ++d)
        acc = fmaf(v[d], W[(rowoff + d) * 64 + h], acc);

    float* dst = (which == 0) ? PAxx : (which == 1) ? PCxx
               : (which == 2) ? PAyx : PCyx;
    dst[blk * 64 + h] = acc;
}

// ---------------------------------------------------------------------------
// Kernel B (r15): r13 pair structure (main loop bit-identical) + head fused
// via last-block pattern.
// r14 failure: volatile z reads in the tail are mutually ORDERED -> serial
// ~768 x 350cy chain = +270 us. r15 fix: one device-scope acquire fence
// (after the counter atomic) then PLAIN vectorized f32x4 reads (overlapped).
// ---------------------------------------------------------------------------
__global__ __launch_bounds__(256, 3) void pair_mfma_kernel(
    const float* __restrict__ PAxx, const float* __restrict__ PCxx,
    const float* __restrict__ PAyx, const float* __restrict__ PCyx,
    const f32x4* __restrict__ W2F,
    float* __restrict__ zxx, float* __restrict__ zyx,
    const float* __restrict__ b2xx, const float* __restrict__ b2yx,
    const float* __restrict__ Wd1, const float* __restrict__ bd1,
    const float* __restrict__ Wd2, const float* __restrict__ bd2,
    unsigned int* __restrict__ counter, float* __restrict__ out)
{
    // XCD-chunked swizzle (bijective: 768 = 8 * 96)
    int bid = blockIdx.x;
    int blk = (bid & 7) * 96 + (bid >> 3);
    int br = blk / 384;
    int ig = blk % 384;              // i-group: bi = ig*4 + w (never straddles b)
    int t = threadIdx.x;
    int w = t >> 6, l = t & 63;
    int g = l >> 4, m = l & 15;
    int bi = ig * 4 + w;
    int b  = bi / N_;

    const float* PA = br ? PAyx : PAxx;
    const float* PC = br ? PCyx : PCxx;

    __shared__ float lbuf[2][32 * LDW_];   // 2 x 8.7 KB

    // B fragments (all 64 k): bf[nt][kt][part], 16 x half8 = 64 regs.
    half8 bf[4][2][2];
    const f32x4* Wb = W2F + br * 1024;
#pragma unroll
    for (int q = 0; q < 16; ++q) {
        frag_cast u;
        u.f = Wb[q * 64 + l];
        asm volatile("" : "+v"(u.f));
        bf[q >> 2][(q >> 1) & 1][q & 1] = u.h;
    }

    // pc values this lane needs: h = kt*32 + g*8 + {0..7}
    f32x4 pcq[4];
#pragma unroll
    for (int kt = 0; kt < 2; ++kt) {
        pcq[kt * 2 + 0] = *(const f32x4*)(PC + bi * 64 + kt * 32 + g * 8);
        pcq[kt * 2 + 1] = *(const f32x4*)(PC + bi * 64 + kt * 32 + g * 8 + 4);
    }

    float mm[4] = {-3.0e38f, -3.0e38f, -3.0e38f, -3.0e38f};

    // staging: thread t stages rows srow and srow+16, 4-float group scg
    int srow = t >> 4;               // 0..15
    int scg  = t & 15;               // 0..15
    const float* gsrc = PA + b * ROW_ + srow * 64 + scg * 4;  // + pt*2048
    int soff = srow * LDW_ + scg * 4;

    // prologue: stage tile-pair 0 into buf 0
    *(f32x4*)(&lbuf[0][0] + soff) = *(const f32x4*)(gsrc);
    *(f32x4*)(&lbuf[0][0] + soff + 16 * LDW_) = *(const f32x4*)(gsrc + 1024);
    __syncthreads();

    const f32x4 vzero = {0.f, 0.f, 0.f, 0.f};
    int cur = 0;

#pragma unroll 1
    for (int pt = 0; pt < NTP_; ++pt) {
        // issue next tile-pair's loads early (hide under this phase's compute)
        f32x4 gn0, gn1;
        if (pt + 1 < NTP_) {
            gn0 = *(const f32x4*)(gsrc + (pt + 1) * 2048);
            gn1 = *(const f32x4*)(gsrc + (pt + 1) * 2048 + 1024);
        }

        // two 16-row subtiles, sequential (ah/al registers reused)
#pragma unroll
        for (int st = 0; st < 2; ++st) {
            const float* lrd = &lbuf[0][0] + cur * (32 * LDW_)
                             + (st * 16 + m) * LDW_ + g * 8;
            f32x4 s0 = *(const f32x4*)(lrd);
            f32x4 s1 = *(const f32x4*)(lrd + 4);
            f32x4 s2 = *(const f32x4*)(lrd + 32);
            f32x4 s3 = *(const f32x4*)(lrd + 36);

            // A-prep: x = relu(pa + pc); split x = hi + lo (pkrtz).
            half8 ah[2], al[2];
#pragma unroll
            for (int kt = 0; kt < 2; ++kt) {
                f32x4 xa = (kt ? s2 : s0) + pcq[kt * 2 + 0];
                f32x4 xb = (kt ? s3 : s1) + pcq[kt * 2 + 1];
                xa = __builtin_elementwise_max(xa, vzero);
                xb = __builtin_elementwise_max(xb, vzero);
                fp16x2* ahp = (fp16x2*)&ah[kt];
                fp16x2* alp = (fp16x2*)&al[kt];
#pragma unroll
                for (int p2 = 0; p2 < 2; ++p2) {
                    fp16x2 hpa = __builtin_amdgcn_cvt_pkrtz(xa[p2 * 2], xa[p2 * 2 + 1]);
                    fp16x2 hpb = __builtin_amdgcn_cvt_pkrtz(xb[p2 * 2], xb[p2 * 2 + 1]);
                    ahp[p2]     = hpa;
                    ahp[p2 + 2] = hpb;
                    alp[p2]     = __builtin_amdgcn_cvt_pkrtz(xa[p2 * 2]     - (float)hpa[0],
                                                             xa[p2 * 2 + 1] - (float)hpa[1]);
                    alp[p2 + 2] = __builtin_amdgcn_cvt_pkrtz(xb[p2 * 2]     - (float)hpb[0],
                                                             xb[p2 * 2 + 1] - (float)hpb[1]);
                }
            }

            // 4 independent accumulator chains (one per nt), depth 6
#pragma unroll
            for (int nt = 0; nt < 4; ++nt) {
                f32x4 a = {0.f, 0.f, 0.f, 0.f};
#pragma unroll
                for (int kt = 0; kt < 2; ++kt) {
                    a = __builtin_amdgcn_mfma_f32_16x16x32_f16(ah[kt], bf[nt][kt][0], a, 0, 0, 0);
                    a = __builtin_amdgcn_mfma_f32_16x16x32_f16(ah[kt], bf[nt][kt][1], a, 0, 0, 0);
                    a = __builtin_amdgcn_mfma_f32_16x16x32_f16(al[kt], bf[nt][kt][0], a, 0, 0, 0);
                }
                mm[nt] = fmaxf(mm[nt],
                               fmaxf(fmaxf(a[0], a[1]), fmaxf(a[2], a[3])));
            }
        }

        // write next tile-pair into the other buffer; one barrier per phase
        if (pt + 1 < NTP_) {
            *(f32x4*)(&lbuf[0][0] + (cur ^ 1) * (32 * LDW_) + soff) = gn0;
            *(f32x4*)(&lbuf[0][0] + (cur ^ 1) * (32 * LDW_) + soff + 16 * LDW_) = gn1;
        }
        __syncthreads();
        cur ^= 1;
    }

    // reduce across the 4 row groups; then every lane holds all 4 nt maxima
#pragma unroll
    for (int nt = 0; nt < 4; ++nt) {
        float v = mm[nt];
        v = fmaxf(v, __shfl_xor(v, 16));
        v = fmaxf(v, __shfl_xor(v, 32));
        mm[nt] = v;
    }
    // lane l owns output column k=l: select mm[l>>4]
    float z = (l < 32) ? ((l < 16) ? mm[0] : mm[1])
                       : ((l < 48) ? mm[2] : mm[3]);
    (br ? zyx : zxx)[bi * 64 + l] = z;

    // ---- last-block head (fused decoder) ----
    __shared__ unsigned int lastflag;
    __threadfence();                  // release our z stores (device scope)
    __syncthreads();                  // all 256 threads' stores+fences done
    if (t == 0) {
        unsigned int old = atomicAdd(counter, 1u);
        lastflag = (old == gridDim.x - 1) ? 1u : 0u;
    }
    __syncthreads();
    if (lastflag) {
        __threadfence();              // acquire (invalidates stale L1/L2)
        __shared__ f32x4 sbuf2[16][16];
        __shared__ float zxs[64];
        int hq = t & 15, ig2 = t >> 4;   // h-quad, i-group
        for (int bb = 0; bb < B_; ++bb) {
            f32x4 s = {0.f, 0.f, 0.f, 0.f};
            for (int i = ig2; i < N_; i += 16) {
                int idx = (bb * N_ + i) * 64 + hq * 4;
                s += *(const f32x4*)(zxx + idx) - *(const f32x4*)(zyx + idx);
            }
            sbuf2[ig2][hq] = s;
            __syncthreads();
            if (t < 64) {
                float acc2 = 0.f;
#pragma unroll
                for (int gg = 0; gg < 16; ++gg)
                    acc2 += sbuf2[gg][t >> 2][t & 3];
                zxs[t] = acc2 + (float)N_ * (b2xx[t] - b2yx[t]);
            }
            __syncthreads();
            if (t < 64) {
                float acc = bd1[t];
#pragma unroll
                for (int d = 0; d < 64; ++d)
                    acc = fmaf(zxs[d], Wd1[d * 64 + t] + Wd1[(64 + d) * 64 + t], acc);
                float h1 = fmaxf(acc, 0.f);
                float r = h1 * Wd2[t];
#pragma unroll
                for (int off = 32; off; off >>= 1) r += __shfl_down(r, off);
                if (t == 0) out[bb] = r + bd2[0];
            }
            __syncthreads();
        }
    }
}

extern "C" void kernel_launch(void* const* d_in, const int* in_sizes, int n_in,
                              void* d_out, int out_size, void* d_ws, size_t ws_size,
                              hipStream_t stream) {
    const float* X    = (const float*)d_in[0];
    const float* Y    = (const float*)d_in[1];
    const float* Wxx1 = (const float*)d_in[2];
    const float* bxx1 = (const float*)d_in[3];
    const float* W2xx = (const float*)d_in[4];
    const float* b2xx = (const float*)d_in[5];
    // d_in[6..9]  = xy branch (dead code)
    const float* Wyx1 = (const float*)d_in[10];
    const float* byx1 = (const float*)d_in[11];
    const float* W2yx = (const float*)d_in[12];
    const float* b2yx = (const float*)d_in[13];
    // d_in[14..17] = yy branch (dead code)
    const float* Wd1  = (const float*)d_in[18];
    const float* bd1  = (const float*)d_in[19];
    const float* Wd2  = (const float*)d_in[20];
    const float* bd2  = (const float*)d_in[21];

    float* ws   = (float*)d_ws;
    float* PAxx = ws;
    float* PCxx = ws + 1 * (BN_ * H_);
    float* PAyx = ws + 2 * (BN_ * H_);
    float* PCyx = ws + 3 * (BN_ * H_);
    float* zxx  = ws + 4 * (BN_ * H_);
    float* zyx  = ws + 5 * (BN_ * H_);
    _Float16* W2F = (_Float16*)(ws + 6 * (BN_ * H_));          // 32 KiB
    unsigned int* counter = (unsigned int*)(ws + 6 * (BN_ * H_) + 8192);

    proj_kernel<<<BN_ + 8, 256, 0, stream>>>(X, Y, Wxx1, bxx1, Wyx1, byx1,
                                             W2xx, W2yx,
                                             PAxx, PCxx, PAyx, PCyx, W2F,
                                             counter);
    pair_mfma_kernel<<<768, 256, 0, stream>>>(PAxx, PCxx, PAyx, PCyx,
                                              (const f32x4*)W2F, zxx, zyx,
                                              b2xx, b2yx, Wd1, bd1, Wd2, bd2,
                                              counter, (float*)d_out);
}

// Round 16
// 65.380 us; speedup vs baseline: 4.7452x; 2.4706x over previous
//
#include <hip/hip_runtime.h>

#define B_ 4
#define N_ 384
#define D_ 64
#define H_ 64
#define BN_ (B_ * N_)   // 1536
#define ROW_ (N_ * H_)  // 24576 floats per batch of PA/PC
#define NTP_ 12         // 32-row j-tile-pairs per batch
#define LDW_ 68         // padded LDS row stride in words (64+4: 2-way max)

typedef float f32x4 __attribute__((ext_vector_type(4)));
typedef _Float16 half8 __attribute__((ext_vector_type(8)));
typedef __fp16 fp16x2 __attribute__((ext_vector_type(2)));   // cvt_pkrtz result type

union frag_cast { f32x4 f; half8 h; };

// ---------------------------------------------------------------------------
// Kernel A: projections (blocks 0..BN_-1) + W2 hi/lo fragment prep
// (blocks BN_..BN_+7).
// W2F layout: [br][q=nt*4+kt*2+part][lane=64][e=8] f16.
//   B element for lane l, elem e: h = kt*32 + (l>>4)*8 + e, n = nt*16 + (l&15)
// ---------------------------------------------------------------------------
__global__ __launch_bounds__(256) void proj_kernel(
    const float* __restrict__ X, const float* __restrict__ Y,
    const float* __restrict__ Wxx1, const float* __restrict__ bxx1,
    const float* __restrict__ Wyx1, const float* __restrict__ byx1,
    const float* __restrict__ W2xx, const float* __restrict__ W2yx,
    float* __restrict__ PAxx, float* __restrict__ PCxx,
    float* __restrict__ PAyx, float* __restrict__ PCyx,
    _Float16* __restrict__ W2F)
{
    if (blockIdx.x >= BN_) {
        int t = (blockIdx.x - BN_) * 256 + threadIdx.x;
        int br = t >> 10;
        int q  = (t >> 6) & 15;
        int l  = t & 63;
        int nt = q >> 2, kt = (q >> 1) & 1, part = q & 1;
        const float* W2 = br ? W2yx : W2xx;
        int n = nt * 16 + (l & 15);
        int g = l >> 4;
        _Float16* dst = W2F + t * 8;
#pragma unroll
        for (int e = 0; e < 8; ++e) {
            int h = kt * 32 + g * 8 + e;
            float v = W2[h * 64 + n];
            _Float16 hi = (_Float16)v;
            _Float16 lo = (_Float16)(v - (float)hi);
            dst[e] = part ? lo : hi;
        }
        return;
    }

    int blk = blockIdx.x;            // b*N + n
    int t = threadIdx.x;
    int which = t >> 6, h = t & 63;

    __shared__ float xrow[64];
    __shared__ float yrow[64];
    if (t < 64) xrow[t] = X[blk * 64 + t];
    else if (t < 128) yrow[t - 64] = Y[blk * 64 + (t - 64)];
    __syncthreads();

    const float* v = (which == 2) ? yrow : xrow;
    const float* W = (which < 2) ? Wxx1 : Wyx1;
    int rowoff = (which & 1) ? 64 : 0;

    float acc = 0.f;
    if (which == 1) acc = bxx1[h];
    if (which == 3) acc = byx1[h];
#pragma unroll
    for (int d = 0; d < 64; ++d)
        acc = fmaf(v[d], W[(rowoff + d) * 64 + h], acc);

    float* dst = (which == 0) ? PAxx : (which == 1) ? PCxx
               : (which == 2) ? PAyx : PCyx;
    dst[blk * 64 + h] = acc;
}

// ---------------------------------------------------------------------------
// Kernel B (r13 verified structure): 768 blocks x 256 thr. Block = (br,
// group of 4 consecutive bi); wave w handles bi = ig*4 + w over ALL 384 j.
// The 4 waves SHARE each staged PA tile via LDS. 32 j-rows (2 subtiles) per
// barrier phase; staged loads issued before compute; 2-buffer ring.
//   z[br][bi][k] = max_j relu(PA[b,j,:]+PC[b,i,:]) . W2[:,k]
// split-f16 MFMA (hi*hi + hi*lo + lo*hi), fp32-grade (absmax 0.0 since r4).
// LDS rows padded to 68 words -> max 2-way bank aliasing (free, m136).
// NOTE r14/r15 lesson: do NOT fuse the head via last-block + device fences —
// per-block __threadfence() (L2 writeback) costs ~100-280 us on MI355X.
// ---------------------------------------------------------------------------
__global__ __launch_bounds__(256, 3) void pair_mfma_kernel(
    const float* __restrict__ PAxx, const float* __restrict__ PCxx,
    const float* __restrict__ PAyx, const float* __restrict__ PCyx,
    const f32x4* __restrict__ W2F,
    float* __restrict__ zxx, float* __restrict__ zyx)
{
    // XCD-chunked swizzle (bijective: 768 = 8 * 96)
    int bid = blockIdx.x;
    int blk = (bid & 7) * 96 + (bid >> 3);
    int br = blk / 384;
    int ig = blk % 384;              // i-group: bi = ig*4 + w (never straddles b)
    int t = threadIdx.x;
    int w = t >> 6, l = t & 63;
    int g = l >> 4, m = l & 15;
    int bi = ig * 4 + w;
    int b  = bi / N_;

    const float* PA = br ? PAyx : PAxx;
    const float* PC = br ? PCyx : PCxx;

    __shared__ float lbuf[2][32 * LDW_];   // 2 x 8.7 KB

    // B fragments (all 64 k): bf[nt][kt][part], 16 x half8 = 64 regs.
    // Opaque pin: value comes out of asm -> rematerialization impossible.
    half8 bf[4][2][2];
    const f32x4* Wb = W2F + br * 1024;
#pragma unroll
    for (int q = 0; q < 16; ++q) {
        frag_cast u;
        u.f = Wb[q * 64 + l];
        asm volatile("" : "+v"(u.f));
        bf[q >> 2][(q >> 1) & 1][q & 1] = u.h;
    }

    // pc values this lane needs: h = kt*32 + g*8 + {0..7}
    f32x4 pcq[4];
#pragma unroll
    for (int kt = 0; kt < 2; ++kt) {
        pcq[kt * 2 + 0] = *(const f32x4*)(PC + bi * 64 + kt * 32 + g * 8);
        pcq[kt * 2 + 1] = *(const f32x4*)(PC + bi * 64 + kt * 32 + g * 8 + 4);
    }

    float mm[4] = {-3.0e38f, -3.0e38f, -3.0e38f, -3.0e38f};

    // staging: thread t stages rows srow and srow+16, 4-float group scg
    int srow = t >> 4;               // 0..15
    int scg  = t & 15;               // 0..15
    const float* gsrc = PA + b * ROW_ + srow * 64 + scg * 4;  // + pt*2048
    int soff = srow * LDW_ + scg * 4;

    // prologue: stage tile-pair 0 into buf 0
    *(f32x4*)(&lbuf[0][0] + soff) = *(const f32x4*)(gsrc);
    *(f32x4*)(&lbuf[0][0] + soff + 16 * LDW_) = *(const f32x4*)(gsrc + 1024);
    __syncthreads();

    const f32x4 vzero = {0.f, 0.f, 0.f, 0.f};
    int cur = 0;

#pragma unroll 1
    for (int pt = 0; pt < NTP_; ++pt) {
        // issue next tile-pair's loads early (hide under this phase's compute)
        f32x4 gn0, gn1;
        if (pt + 1 < NTP_) {
            gn0 = *(const f32x4*)(gsrc + (pt + 1) * 2048);
            gn1 = *(const f32x4*)(gsrc + (pt + 1) * 2048 + 1024);
        }

        // two 16-row subtiles, sequential (ah/al registers reused)
#pragma unroll
        for (int st = 0; st < 2; ++st) {
            const float* lrd = &lbuf[0][0] + cur * (32 * LDW_)
                             + (st * 16 + m) * LDW_ + g * 8;
            f32x4 s0 = *(const f32x4*)(lrd);
            f32x4 s1 = *(const f32x4*)(lrd + 4);
            f32x4 s2 = *(const f32x4*)(lrd + 32);
            f32x4 s3 = *(const f32x4*)(lrd + 36);

            // A-prep: x = relu(pa + pc); split x = hi + lo (pkrtz).
            half8 ah[2], al[2];
#pragma unroll
            for (int kt = 0; kt < 2; ++kt) {
                f32x4 xa = (kt ? s2 : s0) + pcq[kt * 2 + 0];
                f32x4 xb = (kt ? s3 : s1) + pcq[kt * 2 + 1];
                xa = __builtin_elementwise_max(xa, vzero);
                xb = __builtin_elementwise_max(xb, vzero);
                fp16x2* ahp = (fp16x2*)&ah[kt];
                fp16x2* alp = (fp16x2*)&al[kt];
#pragma unroll
                for (int p2 = 0; p2 < 2; ++p2) {
                    fp16x2 hpa = __builtin_amdgcn_cvt_pkrtz(xa[p2 * 2], xa[p2 * 2 + 1]);
                    fp16x2 hpb = __builtin_amdgcn_cvt_pkrtz(xb[p2 * 2], xb[p2 * 2 + 1]);
                    ahp[p2]     = hpa;
                    ahp[p2 + 2] = hpb;
                    alp[p2]     = __builtin_amdgcn_cvt_pkrtz(xa[p2 * 2]     - (float)hpa[0],
                                                             xa[p2 * 2 + 1] - (float)hpa[1]);
                    alp[p2 + 2] = __builtin_amdgcn_cvt_pkrtz(xb[p2 * 2]     - (float)hpb[0],
                                                             xb[p2 * 2 + 1] - (float)hpb[1]);
                }
            }

            // 4 independent accumulator chains (one per nt), depth 6
#pragma unroll
            for (int nt = 0; nt < 4; ++nt) {
                f32x4 a = {0.f, 0.f, 0.f, 0.f};
#pragma unroll
                for (int kt = 0; kt < 2; ++kt) {
                    a = __builtin_amdgcn_mfma_f32_16x16x32_f16(ah[kt], bf[nt][kt][0], a, 0, 0, 0);
                    a = __builtin_amdgcn_mfma_f32_16x16x32_f16(ah[kt], bf[nt][kt][1], a, 0, 0, 0);
                    a = __builtin_amdgcn_mfma_f32_16x16x32_f16(al[kt], bf[nt][kt][0], a, 0, 0, 0);
                }
                mm[nt] = fmaxf(mm[nt],
                               fmaxf(fmaxf(a[0], a[1]), fmaxf(a[2], a[3])));
            }
        }

        // write next tile-pair into the other buffer; one barrier per phase
        if (pt + 1 < NTP_) {
            *(f32x4*)(&lbuf[0][0] + (cur ^ 1) * (32 * LDW_) + soff) = gn0;
            *(f32x4*)(&lbuf[0][0] + (cur ^ 1) * (32 * LDW_) + soff + 16 * LDW_) = gn1;
        }
        __syncthreads();
        cur ^= 1;
    }

    // reduce across the 4 row groups; then every lane holds all 4 nt maxima
#pragma unroll
    for (int nt = 0; nt < 4; ++nt) {
        float v = mm[nt];
        v = fmaxf(v, __shfl_xor(v, 16));
        v = fmaxf(v, __shfl_xor(v, 32));
        mm[nt] = v;
    }
    // lane l owns output column k=l: select mm[l>>4]
    float z = (l < 32) ? ((l < 16) ? mm[0] : mm[1])
                       : ((l < 48) ? mm[2] : mm[3]);
    (br ? zyx : zxx)[bi * 64 + l] = z;
}

// ---------------------------------------------------------------------------
// Kernel C: Z_X[b,h] = sum_i (zxx - zyx) + N*(b2xx - b2yx); decoder.
// z = [Z_X, Z_X] so z@Wd1 = Z_X @ (Wd1[:64] + Wd1[64:]).
// ---------------------------------------------------------------------------
__global__ __launch_bounds__(256) void head_kernel(
    const float* __restrict__ zxx, const float* __restrict__ zyx,
    const float* __restrict__ b2xx, const float* __restrict__ b2yx,
    const float* __restrict__ Wd1, const float* __restrict__ bd1,
    const float* __restrict__ Wd2, const float* __restrict__ bd2,
    float* __restrict__ out)
{
    int b = blockIdx.x;
    int t = threadIdx.x;
    int ig = t >> 6, h = t & 63;

    __shared__ float sbuf[4][64];
    __shared__ float zx[64];

    float s = 0.f;
    for (int i = ig; i < N_; i += 4) {
        int idx = (b * N_ + i) * 64 + h;
        s += zxx[idx] - zyx[idx];
    }
    sbuf[ig][h] = s;
    __syncthreads();
    if (t < 64)
        zx[t] = sbuf[0][t] + sbuf[1][t] + sbuf[2][t] + sbuf[3][t]
              + (float)N_ * (b2xx[t] - b2yx[t]);
    __syncthreads();

    if (t < 64) {
        float acc = bd1[t];
#pragma unroll
        for (int d = 0; d < 64; ++d)
            acc = fmaf(zx[d], Wd1[d * 64 + t] + Wd1[(64 + d) * 64 + t], acc);
        float h1 = fmaxf(acc, 0.f);
        float r = h1 * Wd2[t];
#pragma unroll
        for (int off = 32; off; off >>= 1) r += __shfl_down(r, off);
        if (t == 0) out[b] = r + bd2[0];
    }
}

extern "C" void kernel_launch(void* const* d_in, const int* in_sizes, int n_in,
                              void* d_out, int out_size, void* d_ws, size_t ws_size,
                              hipStream_t stream) {
    const float* X    = (const float*)d_in[0];
    const float* Y    = (const float*)d_in[1];
    const float* Wxx1 = (const float*)d_in[2];
    const float* bxx1 = (const float*)d_in[3];
    const float* W2xx = (const float*)d_in[4];
    const float* b2xx = (const float*)d_in[5];
    // d_in[6..9]  = xy branch (dead code)
    const float* Wyx1 = (const float*)d_in[10];
    const float* byx1 = (const float*)d_in[11];
    const float* W2yx = (const float*)d_in[12];
    const float* b2yx = (const float*)d_in[13];
    // d_in[14..17] = yy branch (dead code)
    const float* Wd1  = (const float*)d_in[18];
    const float* bd1  = (const float*)d_in[19];
    const float* Wd2  = (const float*)d_in[20];
    const float* bd2  = (const float*)d_in[21];

    float* ws   = (float*)d_ws;
    float* PAxx = ws;
    float* PCxx = ws + 1 * (BN_ * H_);
    float* PAyx = ws + 2 * (BN_ * H_);
    float* PCyx = ws + 3 * (BN_ * H_);
    float* zxx  = ws + 4 * (BN_ * H_);
    float* zyx  = ws + 5 * (BN_ * H_);
    _Float16* W2F = (_Float16*)(ws + 6 * (BN_ * H_));  // 32 KiB, 16B-aligned

    proj_kernel<<<BN_ + 8, 256, 0, stream>>>(X, Y, Wxx1, bxx1, Wyx1, byx1,
                                             W2xx, W2yx,
                                             PAxx, PCxx, PAyx, PCyx, W2F);
    pair_mfma_kernel<<<768, 256, 0, stream>>>(PAxx, PCxx, PAyx, PCyx,
                                              (const f32x4*)W2F, zxx, zyx);
    head_kernel<<<B_, 256, 0, stream>>>(zxx, zyx, b2xx, b2yx,
                                        Wd1, bd1, Wd2, bd2, (float*)d_out);
}

// Round 17
// 47.916 us; speedup vs baseline: 6.4747x; 1.3645x over previous
//
#include <hip/hip_runtime.h>

#define B_ 4
#define N_ 384
#define D_ 64
#define H_ 64
#define BN_ (B_ * N_)   // 1536
#define ROW_ (N_ * H_)  // 24576 floats per batch of PA/PC
#define NTP_ 12         // 32-row j-tile-pairs per batch
#define LDW_ 68         // padded LDS row stride in words (64+4: 2-way max)

typedef float f32x4 __attribute__((ext_vector_type(4)));
typedef _Float16 half8 __attribute__((ext_vector_type(8)));
typedef __fp16 fp16x2 __attribute__((ext_vector_type(2)));   // cvt_pkrtz result type

union frag_cast { f32x4 f; half8 h; };

// ---------------------------------------------------------------------------
// Kernel A: projections (blocks 0..BN_-1) + W2 hi/lo fragment prep
// (blocks BN_..BN_+7).
// W2F layout: [br][q=nt*4+kt*2+part][lane=64][e=8] f16.
//   B element for lane l, elem e: h = kt*32 + (l>>4)*8 + e, n = nt*16 + (l&15)
// ---------------------------------------------------------------------------
__global__ __launch_bounds__(256) void proj_kernel(
    const float* __restrict__ X, const float* __restrict__ Y,
    const float* __restrict__ Wxx1, const float* __restrict__ bxx1,
    const float* __restrict__ Wyx1, const float* __restrict__ byx1,
    const float* __restrict__ W2xx, const float* __restrict__ W2yx,
    float* __restrict__ PAxx, float* __restrict__ PCxx,
    float* __restrict__ PAyx, float* __restrict__ PCyx,
    _Float16* __restrict__ W2F)
{
    if (blockIdx.x >= BN_) {
        int t = (blockIdx.x - BN_) * 256 + threadIdx.x;
        int br = t >> 10;
        int q  = (t >> 6) & 15;
        int l  = t & 63;
        int nt = q >> 2, kt = (q >> 1) & 1, part = q & 1;
        const float* W2 = br ? W2yx : W2xx;
        int n = nt * 16 + (l & 15);
        int g = l >> 4;
        _Float16* dst = W2F + t * 8;
#pragma unroll
        for (int e = 0; e < 8; ++e) {
            int h = kt * 32 + g * 8 + e;
            float v = W2[h * 64 + n];
            _Float16 hi = (_Float16)v;
            _Float16 lo = (_Float16)(v - (float)hi);
            dst[e] = part ? lo : hi;
        }
        return;
    }

    int blk = blockIdx.x;            // b*N + n
    int t = threadIdx.x;
    int which = t >> 6, h = t & 63;

    __shared__ float xrow[64];
    __shared__ float yrow[64];
    if (t < 64) xrow[t] = X[blk * 64 + t];
    else if (t < 128) yrow[t - 64] = Y[blk * 64 + (t - 64)];
    __syncthreads();

    const float* v = (which == 2) ? yrow : xrow;
    const float* W = (which < 2) ? Wxx1 : Wyx1;
    int rowoff = (which & 1) ? 64 : 0;

    float acc = 0.f;
    if (which == 1) acc = bxx1[h];
    if (which == 3) acc = byx1[h];
#pragma unroll
    for (int d = 0; d < 64; ++d)
        acc = fmaf(v[d], W[(rowoff + d) * 64 + h], acc);

    float* dst = (which == 0) ? PAxx : (which == 1) ? PCxx
               : (which == 2) ? PAyx : PCyx;
    dst[blk * 64 + h] = acc;
}

// ---------------------------------------------------------------------------
// Kernel B (r17): r13 verified main loop; NEW epilogue sums the block's 4
// i-rows in LDS and writes ONE 64-float partial per block:
//   zsum[br][ig][k] = sum_{w=0..3} max_j relu(PA[b,j,:]+PC[ig*4+w,:]).W2[:,k]
// This shrinks head's input 8x (1.5 MB -> 196 KB): the head tail was a
// 4-block latency-bound read. All else identical to r13 (absmax 0.0 lineage;
// the i-sum association order changes -> absmax may be ~1e-5, fp32-grade).
// NOTE r14/r15 lesson: no last-block fusion — per-block device fences cost
// ~100-280 us on MI355X.
// ---------------------------------------------------------------------------
__global__ __launch_bounds__(256, 3) void pair_mfma_kernel(
    const float* __restrict__ PAxx, const float* __restrict__ PCxx,
    const float* __restrict__ PAyx, const float* __restrict__ PCyx,
    const f32x4* __restrict__ W2F,
    float* __restrict__ zxxs, float* __restrict__ zyxs)
{
    // XCD-chunked swizzle (bijective: 768 = 8 * 96)
    int bid = blockIdx.x;
    int blk = (bid & 7) * 96 + (bid >> 3);
    int br = blk / 384;
    int ig = blk % 384;              // i-group: bi = ig*4 + w (never straddles b)
    int t = threadIdx.x;
    int w = t >> 6, l = t & 63;
    int g = l >> 4, m = l & 15;
    int bi = ig * 4 + w;
    int b  = bi / N_;

    const float* PA = br ? PAyx : PAxx;
    const float* PC = br ? PCyx : PCxx;

    __shared__ float lbuf[2][32 * LDW_];   // 2 x 8.7 KB
    __shared__ float zsums[4][64];         // epilogue i-sum buffer

    // B fragments (all 64 k): bf[nt][kt][part], 16 x half8 = 64 regs.
    // Opaque pin: value comes out of asm -> rematerialization impossible.
    half8 bf[4][2][2];
    const f32x4* Wb = W2F + br * 1024;
#pragma unroll
    for (int q = 0; q < 16; ++q) {
        frag_cast u;
        u.f = Wb[q * 64 + l];
        asm volatile("" : "+v"(u.f));
        bf[q >> 2][(q >> 1) & 1][q & 1] = u.h;
    }

    // pc values this lane needs: h = kt*32 + g*8 + {0..7}
    f32x4 pcq[4];
#pragma unroll
    for (int kt = 0; kt < 2; ++kt) {
        pcq[kt * 2 + 0] = *(const f32x4*)(PC + bi * 64 + kt * 32 + g * 8);
        pcq[kt * 2 + 1] = *(const f32x4*)(PC + bi * 64 + kt * 32 + g * 8 + 4);
    }

    float mm[4] = {-3.0e38f, -3.0e38f, -3.0e38f, -3.0e38f};

    // staging: thread t stages rows srow and srow+16, 4-float group scg
    int srow = t >> 4;               // 0..15
    int scg  = t & 15;               // 0..15
    const float* gsrc = PA + b * ROW_ + srow * 64 + scg * 4;  // + pt*2048
    int soff = srow * LDW_ + scg * 4;

    // prologue: stage tile-pair 0 into buf 0
    *(f32x4*)(&lbuf[0][0] + soff) = *(const f32x4*)(gsrc);
    *(f32x4*)(&lbuf[0][0] + soff + 16 * LDW_) = *(const f32x4*)(gsrc + 1024);
    __syncthreads();

    const f32x4 vzero = {0.f, 0.f, 0.f, 0.f};
    int cur = 0;

#pragma unroll 1
    for (int pt = 0; pt < NTP_; ++pt) {
        // issue next tile-pair's loads early (hide under this phase's compute)
        f32x4 gn0, gn1;
        if (pt + 1 < NTP_) {
            gn0 = *(const f32x4*)(gsrc + (pt + 1) * 2048);
            gn1 = *(const f32x4*)(gsrc + (pt + 1) * 2048 + 1024);
        }

        // two 16-row subtiles, sequential (ah/al registers reused)
#pragma unroll
        for (int st = 0; st < 2; ++st) {
            const float* lrd = &lbuf[0][0] + cur * (32 * LDW_)
                             + (st * 16 + m) * LDW_ + g * 8;
            f32x4 s0 = *(const f32x4*)(lrd);
            f32x4 s1 = *(const f32x4*)(lrd + 4);
            f32x4 s2 = *(const f32x4*)(lrd + 32);
            f32x4 s3 = *(const f32x4*)(lrd + 36);

            // A-prep: x = relu(pa + pc); split x = hi + lo (pkrtz).
            half8 ah[2], al[2];
#pragma unroll
            for (int kt = 0; kt < 2; ++kt) {
                f32x4 xa = (kt ? s2 : s0) + pcq[kt * 2 + 0];
                f32x4 xb = (kt ? s3 : s1) + pcq[kt * 2 + 1];
                xa = __builtin_elementwise_max(xa, vzero);
                xb = __builtin_elementwise_max(xb, vzero);
                fp16x2* ahp = (fp16x2*)&ah[kt];
                fp16x2* alp = (fp16x2*)&al[kt];
#pragma unroll
                for (int p2 = 0; p2 < 2; ++p2) {
                    fp16x2 hpa = __builtin_amdgcn_cvt_pkrtz(xa[p2 * 2], xa[p2 * 2 + 1]);
                    fp16x2 hpb = __builtin_amdgcn_cvt_pkrtz(xb[p2 * 2], xb[p2 * 2 + 1]);
                    ahp[p2]     = hpa;
                    ahp[p2 + 2] = hpb;
                    alp[p2]     = __builtin_amdgcn_cvt_pkrtz(xa[p2 * 2]     - (float)hpa[0],
                                                             xa[p2 * 2 + 1] - (float)hpa[1]);
                    alp[p2 + 2] = __builtin_amdgcn_cvt_pkrtz(xb[p2 * 2]     - (float)hpb[0],
                                                             xb[p2 * 2 + 1] - (float)hpb[1]);
                }
            }

            // 4 independent accumulator chains (one per nt), depth 6
#pragma unroll
            for (int nt = 0; nt < 4; ++nt) {
                f32x4 a = {0.f, 0.f, 0.f, 0.f};
#pragma unroll
                for (int kt = 0; kt < 2; ++kt) {
                    a = __builtin_amdgcn_mfma_f32_16x16x32_f16(ah[kt], bf[nt][kt][0], a, 0, 0, 0);
                    a = __builtin_amdgcn_mfma_f32_16x16x32_f16(ah[kt], bf[nt][kt][1], a, 0, 0, 0);
                    a = __builtin_amdgcn_mfma_f32_16x16x32_f16(al[kt], bf[nt][kt][0], a, 0, 0, 0);
                }
                mm[nt] = fmaxf(mm[nt],
                               fmaxf(fmaxf(a[0], a[1]), fmaxf(a[2], a[3])));
            }
        }

        // write next tile-pair into the other buffer; one barrier per phase
        if (pt + 1 < NTP_) {
            *(f32x4*)(&lbuf[0][0] + (cur ^ 1) * (32 * LDW_) + soff) = gn0;
            *(f32x4*)(&lbuf[0][0] + (cur ^ 1) * (32 * LDW_) + soff + 16 * LDW_) = gn1;
        }
        __syncthreads();
        cur ^= 1;
    }

    // reduce across the 4 row groups; then every lane holds all 4 nt maxima
#pragma unroll
    for (int nt = 0; nt < 4; ++nt) {
        float v = mm[nt];
        v = fmaxf(v, __shfl_xor(v, 16));
        v = fmaxf(v, __shfl_xor(v, 32));
        mm[nt] = v;
    }
    // lane l owns output column k=l: select mm[l>>4]
    float z = (l < 32) ? ((l < 16) ? mm[0] : mm[1])
                       : ((l < 48) ? mm[2] : mm[3]);

    // block-level sum over the 4 i's (one per wave), deterministic order
    zsums[w][l] = z;
    __syncthreads();
    if (w == 0) {
        float s = ((zsums[0][l] + zsums[1][l]) + zsums[2][l]) + zsums[3][l];
        (br ? zyxs : zxxs)[ig * 64 + l] = s;
    }
}

// ---------------------------------------------------------------------------
// Kernel C: Z_X[b,h] = sum_{q} (zxxs[b*96+q] - zyxs[b*96+q]) + N*(b2xx-b2yx);
// decoder. z = [Z_X, Z_X] so z@Wd1 = Z_X @ (Wd1[:64] + Wd1[64:]).
// Input is now 196 KB (vs 1.5 MB) — 96 partials per batch.
// ---------------------------------------------------------------------------
__global__ __launch_bounds__(256) void head_kernel(
    const float* __restrict__ zxxs, const float* __restrict__ zyxs,
    const float* __restrict__ b2xx, const float* __restrict__ b2yx,
    const float* __restrict__ Wd1, const float* __restrict__ bd1,
    const float* __restrict__ Wd2, const float* __restrict__ bd2,
    float* __restrict__ out)
{
    int b = blockIdx.x;
    int t = threadIdx.x;
    int ig = t >> 6, h = t & 63;

    __shared__ float sbuf[4][64];
    __shared__ float zx[64];

    float s = 0.f;
    for (int q = ig; q < 96; q += 4) {
        int idx = (b * 96 + q) * 64 + h;
        s += zxxs[idx] - zyxs[idx];
    }
    sbuf[ig][h] = s;
    __syncthreads();
    if (t < 64)
        zx[t] = sbuf[0][t] + sbuf[1][t] + sbuf[2][t] + sbuf[3][t]
              + (float)N_ * (b2xx[t] - b2yx[t]);
    __syncthreads();

    if (t < 64) {
        float acc = bd1[t];
#pragma unroll
        for (int d = 0; d < 64; ++d)
            acc = fmaf(zx[d], Wd1[d * 64 + t] + Wd1[(64 + d) * 64 + t], acc);
        float h1 = fmaxf(acc, 0.f);
        float r = h1 * Wd2[t];
#pragma unroll
        for (int off = 32; off; off >>= 1) r += __shfl_down(r, off);
        if (t == 0) out[b] = r + bd2[0];
    }
}

extern "C" void kernel_launch(void* const* d_in, const int* in_sizes, int n_in,
                              void* d_out, int out_size, void* d_ws, size_t ws_size,
                              hipStream_t stream) {
    const float* X    = (const float*)d_in[0];
    const float* Y    = (const float*)d_in[1];
    const float* Wxx1 = (const float*)d_in[2];
    const float* bxx1 = (const float*)d_in[3];
    const float* W2xx = (const float*)d_in[4];
    const float* b2xx = (const float*)d_in[5];
    // d_in[6..9]  = xy branch (dead code)
    const float* Wyx1 = (const float*)d_in[10];
    const float* byx1 = (const float*)d_in[11];
    const float* W2yx = (const float*)d_in[12];
    const float* b2yx = (const float*)d_in[13];
    // d_in[14..17] = yy branch (dead code)
    const float* Wd1  = (const float*)d_in[18];
    const float* bd1  = (const float*)d_in[19];
    const float* Wd2  = (const float*)d_in[20];
    const float* bd2  = (const float*)d_in[21];

    float* ws   = (float*)d_ws;
    float* PAxx = ws;
    float* PCxx = ws + 1 * (BN_ * H_);
    float* PAyx = ws + 2 * (BN_ * H_);
    float* PCyx = ws + 3 * (BN_ * H_);
    float* zxxs = ws + 4 * (BN_ * H_);                 // 384*64 floats
    float* zyxs = ws + 4 * (BN_ * H_) + 384 * 64;      // 384*64 floats
    _Float16* W2F = (_Float16*)(ws + 5 * (BN_ * H_));  // 32 KiB, 16B-aligned

    proj_kernel<<<BN_ + 8, 256, 0, stream>>>(X, Y, Wxx1, bxx1, Wyx1, byx1,
                                             W2xx, W2yx,
                                             PAxx, PCxx, PAyx, PCyx, W2F);
    pair_mfma_kernel<<<768, 256, 0, stream>>>(PAxx, PCxx, PAyx, PCyx,
                                              (const f32x4*)W2F, zxxs, zyxs);
    head_kernel<<<B_, 256, 0, stream>>>(zxxs, zyxs, b2xx, b2yx,
                                        Wd1, bd1, Wd2, bd2, (float*)d_out);
}